// Round 3
// baseline (251.273 us; speedup 1.0000x reference)
//
#include <hip/hip_runtime.h>
#include <hip/hip_bf16.h>

typedef __attribute__((ext_vector_type(4))) float f32x4;
typedef __attribute__((ext_vector_type(8))) __bf16 bf16x8;
typedef unsigned short u16;
typedef unsigned int u32;
typedef __attribute__((ext_vector_type(4))) u16 u16x4;

// ---------- helpers ----------
__device__ __forceinline__ u16 f2bf(float f) {
    u32 u = __builtin_bit_cast(u32, f);
    u32 r = (u + 0x7FFFu + ((u >> 16) & 1u)) >> 16;
    return (u16)r;
}
__device__ __forceinline__ float bf2f(u16 h) {
    return __builtin_bit_cast(float, ((u32)h) << 16);
}
__device__ __forceinline__ bf16x8 ld_frag(const u16* p) {
    uint4 v = *reinterpret_cast<const uint4*>(p);
    return __builtin_bit_cast(bf16x8, v);
}
__device__ __forceinline__ void gld_lds(const u16* gp, u16* lp) {
    __builtin_amdgcn_global_load_lds(
        (const __attribute__((address_space(1))) u32*)gp,
        (__attribute__((address_space(3))) u32*)lp, 16, 0, 0);
}
__device__ __forceinline__ u32 pk_bf16(float lo, float hi) {
    u32 r;
    asm("v_cvt_pk_bf16_f32 %0, %1, %2" : "=v"(r) : "v"(lo), "v"(hi));
    return r;
}
__device__ __forceinline__ void unp8(uint4 v, float* f) {
    f[0] = bf2f((u16)(v.x & 0xffffu)); f[1] = bf2f((u16)(v.x >> 16));
    f[2] = bf2f((u16)(v.y & 0xffffu)); f[3] = bf2f((u16)(v.y >> 16));
    f[4] = bf2f((u16)(v.z & 0xffffu)); f[5] = bf2f((u16)(v.z >> 16));
    f[6] = bf2f((u16)(v.w & 0xffffu)); f[7] = bf2f((u16)(v.w >> 16));
}

// ---------- fp32 -> bf16 convert (x4 vectorized) ----------
__global__ __launch_bounds__(256) void cvt_bf16(const float* __restrict__ in,
                                                u16* __restrict__ out, int n4) {
    int i = blockIdx.x * 256 + threadIdx.x;
    if (i < n4) {
        float4 v = reinterpret_cast<const float4*>(in)[i];
        u16x4 o;
        o.x = f2bf(v.x); o.y = f2bf(v.y); o.z = f2bf(v.z); o.w = f2bf(v.w);
        *reinterpret_cast<u16x4*>(out + 4 * (size_t)i) = o;
    }
}

// ---------- rope tables: ctab/stab [T=4096][64] fp32 ----------
__global__ __launch_bounds__(256) void rope_tab(float* __restrict__ ctab,
                                                float* __restrict__ stab) {
    int i = blockIdx.x * 256 + threadIdx.x;
    int t = i >> 6, j = i & 63;
    float c = 1.0f, s = 0.0f;
    if (j < 32) {
        float f = exp2f(-10.0f * (float)j / 31.0f);
        float th = (float)t * f;
        c = cosf(th); s = sinf(th);
    }
    ctab[i] = c; stab[i] = s;
}

// ---------- queue counter init ----------
__global__ void zero_ctr(u32* ctr) { *ctr = 0; }

// ---------- NT GEMM: C[M][N] = A[M][K] * B[N][K]^T, bf16 in, fp32 acc ----------
template <bool OUT_BF16>
__global__ __launch_bounds__(256) void gemm_nt(const u16* __restrict__ A,
                                               const u16* __restrict__ B,
                                               void* __restrict__ Cout,
                                               int M, int N, int K, int ldc) {
    __shared__ u16 sA[2][128 * 32];
    __shared__ u16 sB[2][128 * 32];
    const int tid = threadIdx.x;
    const int w = tid >> 6, l = tid & 63;
    const int mb = M >> 7;
    const int bm = blockIdx.x % mb, bn = blockIdx.x / mb;
    const int g = l >> 4, c16 = l & 15;
    const int srow = l >> 2, ssl = l & 3;
    const int wr = w >> 1, wc = w & 1;

    f32x4 acc[4][4] = {};

    auto stage = [&](int bi, int kt) {
#pragma unroll
        for (int cc = 0; cc < 2; ++cc) {
            int c = 2 * w + cc;
            int r = 16 * c + srow;
            int gs = ssl ^ ((r >> 1) & 3);
            gld_lds(A + (size_t)(bm * 128 + r) * K + kt * 32 + gs * 8, &sA[bi][c * 512]);
            gld_lds(B + (size_t)(bn * 128 + r) * K + kt * 32 + gs * 8, &sB[bi][c * 512]);
        }
    };

    const int NT = K >> 5;
    stage(0, 0);
    __syncthreads();
    for (int kt = 0; kt < NT; ++kt) {
        int cur = kt & 1;
        if (kt + 1 < NT) stage(cur ^ 1, kt + 1);
        bf16x8 af[4], bf[4];
#pragma unroll
        for (int mi = 0; mi < 4; ++mi) {
            int r = wr * 64 + mi * 16 + c16;
            int sl = g ^ ((r >> 1) & 3);
            af[mi] = ld_frag(&sA[cur][r * 32 + sl * 8]);
        }
#pragma unroll
        for (int ni = 0; ni < 4; ++ni) {
            int r = wc * 64 + ni * 16 + c16;
            int sl = g ^ ((r >> 1) & 3);
            bf[ni] = ld_frag(&sB[cur][r * 32 + sl * 8]);
        }
#pragma unroll
        for (int mi = 0; mi < 4; ++mi)
#pragma unroll
            for (int ni = 0; ni < 4; ++ni)
                acc[mi][ni] = __builtin_amdgcn_mfma_f32_16x16x32_bf16(
                    af[mi], bf[ni], acc[mi][ni], 0, 0, 0);
        __syncthreads();
    }
#pragma unroll
    for (int mi = 0; mi < 4; ++mi) {
#pragma unroll
        for (int ni = 0; ni < 4; ++ni) {
            int col = bn * 128 + wc * 64 + ni * 16 + c16;
            int row0 = bm * 128 + wr * 64 + mi * 16 + g * 4;
#pragma unroll
            for (int r = 0; r < 4; ++r) {
                if (OUT_BF16)
                    ((u16*)Cout)[(size_t)(row0 + r) * ldc + col] = f2bf(acc[mi][ni][r]);
                else
                    ((float*)Cout)[(size_t)(row0 + r) * ldc + col] = acc[mi][ni][r];
            }
        }
    }
}

// ---------- prep: rmsnorm+rope on q,k (q pre-scaled by ATTN_SCALE); v-mix ----------
__global__ __launch_bounds__(256) void prep(const u16* __restrict__ qkvb,
                                            const float* __restrict__ ve,
                                            const float* __restrict__ lambdas,
                                            const float* __restrict__ ctab,
                                            const float* __restrict__ stab,
                                            u16* __restrict__ Qb, u16* __restrict__ Kb,
                                            u16* __restrict__ Vt) {
    __shared__ u16 sV[128 * 72];
    const int h = blockIdx.x >> 6, tb = blockIdx.x & 63;
    const int tid = threadIdx.x;
    const int trow = tid >> 2, p = tid & 3;
    const int t = tb * 64 + trow;
    const float l0 = lambdas[0], l1 = lambdas[1];

#pragma unroll
    for (int which = 0; which < 2; ++which) {
        const u16* src = qkvb + (size_t)t * 3072 + which * 1024 + h * 128;
        int j0 = p * 16;
        float x1[16], x2[16];
        unp8(*(const uint4*)(src + j0), x1);
        unp8(*(const uint4*)(src + j0 + 8), x1 + 8);
        unp8(*(const uint4*)(src + 64 + j0), x2);
        unp8(*(const uint4*)(src + 64 + j0 + 8), x2 + 8);
        float ss = 0.0f;
#pragma unroll
        for (int e = 0; e < 16; ++e) ss += x1[e] * x1[e] + x2[e] * x2[e];
        ss += __shfl_xor(ss, 1);
        ss += __shfl_xor(ss, 2);
        float rs = rsqrtf(ss * (1.0f / 128.0f) + 1.1920929e-07f);
        float scl = which ? 1.0f : 0.12f;
        rs *= scl;
        u16* dst = (which ? Kb : Qb) + ((size_t)h * 4096 + t) * 128;
#pragma unroll
        for (int e = 0; e < 16; ++e) {
            int j = j0 + e;
            float c = ctab[t * 64 + j], s = stab[t * 64 + j];
            float a = x1[e] * rs, b = x2[e] * rs;
            dst[j] = f2bf(a * c + b * s);
            dst[j + 64] = f2bf(b * c - a * s);
        }
    }
    {
        const u16* vsrc = qkvb + (size_t)t * 3072 + 2048 + h * 128 + p * 32;
        const float* vesrc = ve + (size_t)t * 1024 + h * 128 + p * 32;
#pragma unroll
        for (int e = 0; e < 32; ++e) {
            float vv = l0 * bf2f(vsrc[e]) + l1 * vesrc[e];
            sV[(p * 32 + e) * 72 + trow] = f2bf(vv);
        }
    }
    __syncthreads();
    {
        int d = tid >> 1, seg = tid & 1;
        const u16* lsrc = &sV[d * 72 + seg * 32];
        u16* gdst = Vt + ((size_t)h * 128 + d) * 4096 + tb * 64 + seg * 32;
#pragma unroll
        for (int q2 = 0; q2 < 4; ++q2)
            *(uint4*)(gdst + q2 * 8) = *(const uint4*)(lsrc + q2 * 8);
    }
}

// ---------- causal flash attention v3 ----------
// 2-wave blocks (128 thr); each wave owns 32 q (two 16-col subtiles u=0,1) so
// every K/V LDS fragment read feeds 2 MFMAs (halves LDS read traffic).
// Dynamic work queue (512 items heavy-first) fixes CU load imbalance.
__global__ __launch_bounds__(128) void attn(const u16* __restrict__ Qb,
                                            const u16* __restrict__ Kb,
                                            const u16* __restrict__ Vt,
                                            u16* __restrict__ Y,
                                            u32* __restrict__ ctr) {
    __shared__ u16 sK[2][64 * 128];   // [kv][d], slot ^= (kv&7)
    __shared__ u16 sV[2][128 * 64];   // [d][kv], slot ^= (d&7)
    __shared__ u16 sP[2][32 * 64];    // per-wave P^T [q][kv], slot ^= (q&7)
    __shared__ int sIdx;
    const int tid = threadIdx.x;
    const int w = tid >> 6, l = tid & 63;
    const int g = l >> 4, q16 = l & 15;
    u16* sPw = &sP[w][0];

    for (;;) {
        if (tid == 0) sIdx = atomicAdd(ctr, 1);
        __syncthreads();
        const int idx = sIdx;
        if (idx >= 512) break;
        const int qb = 63 - (idx >> 3);    // heavy first
        const int h = idx & 7;
        const int qg0 = qb * 64 + w * 32 + q16;        // u=0 q row
        const int qg1 = qg0 + 16;                      // u=1 q row

        // Q fragments: qf[u][dk]
        bf16x8 qf[2][4];
#pragma unroll
        for (int u = 0; u < 2; ++u) {
            const u16* qp = Qb + ((size_t)h * 4096 + (u ? qg1 : qg0)) * 128;
#pragma unroll
            for (int dk = 0; dk < 4; ++dk)
                qf[u][dk] = ld_frag(qp + dk * 32 + g * 8);
        }

        f32x4 o[2][8] = {};
        float m[2] = {-3.0e38f, -3.0e38f};
        float ssum[2] = {0.0f, 0.0f};

        auto stage = [&](int bi, int t) {
#pragma unroll
            for (int cc = 0; cc < 8; ++cc) {
                int c = 8 * w + cc;
                {
                    int r = 4 * c + (l >> 4);
                    int gs = (l & 15) ^ (r & 7);
                    gld_lds(Kb + ((size_t)h * 4096 + t * 64 + r) * 128 + gs * 8,
                            &sK[bi][c * 512]);
                }
                {
                    int r = 8 * c + (l >> 3);
                    int gs = (l & 7) ^ (r & 7);
                    gld_lds(Vt + ((size_t)h * 128 + r) * 4096 + t * 64 + gs * 8,
                            &sV[bi][c * 512]);
                }
            }
        };

        stage(0, 0);
        __syncthreads();

        const int nt = qb + 1;
        for (int t = 0; t < nt; ++t) {
            const int cur = t & 1;
            if (t + 1 < nt) stage(cur ^ 1, t + 1);

            // S^T = K · Q : st[u][ct], each K-frag feeds both u
            f32x4 st[2][4] = {};
            __builtin_amdgcn_s_setprio(1);
#pragma unroll
            for (int ct = 0; ct < 4; ++ct) {
                int row = ct * 16 + q16;
#pragma unroll
                for (int dk = 0; dk < 4; ++dk) {
                    int sl = (dk * 4 + g) ^ (row & 7);
                    bf16x8 kf = ld_frag(&sK[cur][row * 128 + sl * 8]);
                    st[0][ct] = __builtin_amdgcn_mfma_f32_16x16x32_bf16(kf, qf[0][dk], st[0][ct], 0, 0, 0);
                    st[1][ct] = __builtin_amdgcn_mfma_f32_16x16x32_bf16(kf, qf[1][dk], st[1][ct], 0, 0, 0);
                }
            }
            __builtin_amdgcn_s_setprio(0);

            // softmax per u (in-register, lane owns q col; kv spread over g-lanes)
#pragma unroll
            for (int u = 0; u < 2; ++u) {
                const int qg = u ? qg1 : qg0;
                float pv[16];
#pragma unroll
                for (int ct = 0; ct < 4; ++ct)
#pragma unroll
                    for (int r = 0; r < 4; ++r) {
                        int kvg = t * 64 + ct * 16 + g * 4 + r;
                        float v = st[u][ct][r];
                        pv[ct * 4 + r] = (kvg <= qg) ? v : -3.0e38f;
                    }
                float m1[8], m2[4];
#pragma unroll
                for (int i = 0; i < 8; ++i) m1[i] = fmaxf(pv[i], pv[i + 8]);
#pragma unroll
                for (int i = 0; i < 4; ++i) m2[i] = fmaxf(m1[i], m1[i + 4]);
                float tm = fmaxf(fmaxf(m2[0], m2[1]), fmaxf(m2[2], m2[3]));
                tm = fmaxf(tm, __shfl_xor(tm, 16));
                tm = fmaxf(tm, __shfl_xor(tm, 32));
                if (!__all(tm <= m[u] + 8.0f)) {       // defer-max (T13)
                    float nm = fmaxf(m[u], tm);
                    float corr = __expf(m[u] - nm);
                    m[u] = nm;
                    ssum[u] *= corr;
#pragma unroll
                    for (int i = 0; i < 8; ++i) o[u][i] *= corr;
                }
                float ps = 0.0f;
#pragma unroll
                for (int i = 0; i < 16; ++i) {
                    pv[i] = __expf(pv[i] - m[u]);
                    ps += pv[i];
                }
                ps += __shfl_xor(ps, 16);
                ps += __shfl_xor(ps, 32);
                ssum[u] += ps;

                // pack P -> sPw[row = u*16+q16][kv], b32 writes, slot ^= (q16&7)
                const int prow = u * 16 + q16;
#pragma unroll
                for (int ct = 0; ct < 4; ++ct)
#pragma unroll
                    for (int rp = 0; rp < 2; ++rp) {
                        u32 pk = pk_bf16(pv[ct * 4 + 2 * rp], pv[ct * 4 + 2 * rp + 1]);
                        int cu = 8 * ct + 2 * g + rp;
                        int slot = cu >> 2, within = cu & 3;
                        *(u32*)((char*)sPw + prow * 128 + ((slot ^ (q16 & 7)) << 4) + within * 4) = pk;
                    }
            }
            asm volatile("s_waitcnt lgkmcnt(0)" ::: "memory");
            __builtin_amdgcn_sched_barrier(0);

            // O^T += V^T · P^T ; each V-frag feeds both u
            __builtin_amdgcn_s_setprio(1);
#pragma unroll
            for (int kk = 0; kk < 2; ++kk) {
                int slr = (4 * kk + g) ^ (q16 & 7);
                bf16x8 pb0 = ld_frag((const u16*)((const char*)sPw + q16 * 128 + (slr << 4)));
                bf16x8 pb1 = ld_frag((const u16*)((const char*)sPw + (16 + q16) * 128 + (slr << 4)));
#pragma unroll
                for (int n8 = 0; n8 < 8; ++n8) {
                    int row = n8 * 16 + q16;
                    int sl = (4 * kk + g) ^ (row & 7);
                    bf16x8 vf = ld_frag(&sV[cur][row * 64 + sl * 8]);
                    o[0][n8] = __builtin_amdgcn_mfma_f32_16x16x32_bf16(vf, pb0, o[0][n8], 0, 0, 0);
                    o[1][n8] = __builtin_amdgcn_mfma_f32_16x16x32_bf16(vf, pb1, o[1][n8], 0, 0, 0);
                }
            }
            __builtin_amdgcn_s_setprio(0);
            __syncthreads();   // drains next-tile staging
        }

        // epilogue
#pragma unroll
        for (int u = 0; u < 2; ++u) {
            float inv = 1.0f / ssum[u];
            u16* yrow = Y + (size_t)(u ? qg1 : qg0) * 1024 + h * 128;
#pragma unroll
            for (int n8 = 0; n8 < 8; ++n8) {
                int d0 = n8 * 16 + g * 4;
                u16x4 ov;
                ov.x = f2bf(o[u][n8][0] * inv);
                ov.y = f2bf(o[u][n8][1] * inv);
                ov.z = f2bf(o[u][n8][2] * inv);
                ov.w = f2bf(o[u][n8][3] * inv);
                *(u16x4*)(yrow + d0) = ov;
            }
        }
        // item's barriers above guarantee sIdx consumed before next write
    }
}

// ---------- launch ----------
extern "C" void kernel_launch(void* const* d_in, const int* in_sizes, int n_in,
                              void* d_out, int out_size, void* d_ws, size_t ws_size,
                              hipStream_t stream) {
    const float* x = (const float*)d_in[0];
    const float* ve = (const float*)d_in[1];
    const float* qkv_w = (const float*)d_in[2];
    const float* lambdas = (const float*)d_in[3];
    const float* c_proj_w = (const float*)d_in[4];

    char* ws = (char*)d_ws;
    size_t o = 0;
    u16* qkvb = (u16*)(ws + o); o += (size_t)4096 * 3072 * 2;
    u16* xb   = (u16*)(ws + o); o += (size_t)4096 * 1024 * 2;
    u16* wb   = (u16*)(ws + o); o += (size_t)3072 * 1024 * 2;
    u16* cb   = (u16*)(ws + o); o += (size_t)1024 * 1024 * 2;
    u16* Qb   = (u16*)(ws + o); o += (size_t)8 * 4096 * 128 * 2;
    u16* Kb   = (u16*)(ws + o); o += (size_t)8 * 4096 * 128 * 2;
    u16* Vt   = (u16*)(ws + o); o += (size_t)8 * 4096 * 128 * 2;
    u16* Yb   = (u16*)(ws + o); o += (size_t)4096 * 1024 * 2;
    float* ctab = (float*)(ws + o); o += (size_t)4096 * 64 * 4;
    float* stab = (float*)(ws + o); o += (size_t)4096 * 64 * 4;
    u32* ctr  = (u32*)(ws + o); o += 256;

    cvt_bf16<<<4096, 256, 0, stream>>>(x, xb, 4096 * 1024 / 4);
    cvt_bf16<<<3072, 256, 0, stream>>>(qkv_w, wb, 3072 * 1024 / 4);
    cvt_bf16<<<1024, 256, 0, stream>>>(c_proj_w, cb, 1024 * 1024 / 4);
    rope_tab<<<1024, 256, 0, stream>>>(ctab, stab);
    zero_ctr<<<1, 1, 0, stream>>>(ctr);
    gemm_nt<true><<<32 * 24, 256, 0, stream>>>(xb, wb, qkvb, 4096, 3072, 1024, 3072);
    prep<<<512, 256, 0, stream>>>(qkvb, ve, lambdas, ctab, stab, Qb, Kb, Vt);
    attn<<<448, 128, 0, stream>>>(Qb, Kb, Vt, Yb, ctr);
    gemm_nt<false><<<32 * 8, 256, 0, stream>>>(Yb, cb, d_out, 4096, 1024, 1024, 1024);
}

// Round 4
// 175.683 us; speedup vs baseline: 1.4303x; 1.4303x over previous
//
#include <hip/hip_runtime.h>
#include <hip/hip_bf16.h>

typedef __attribute__((ext_vector_type(4))) float f32x4;
typedef __attribute__((ext_vector_type(8))) __bf16 bf16x8;
typedef unsigned short u16;
typedef unsigned int u32;
typedef __attribute__((ext_vector_type(4))) u16 u16x4;

// ---------- helpers ----------
__device__ __forceinline__ u16 f2bf(float f) {
    u32 u = __builtin_bit_cast(u32, f);
    u32 r = (u + 0x7FFFu + ((u >> 16) & 1u)) >> 16;
    return (u16)r;
}
__device__ __forceinline__ float bf2f(u16 h) {
    return __builtin_bit_cast(float, ((u32)h) << 16);
}
__device__ __forceinline__ bf16x8 ld_frag(const u16* p) {
    uint4 v = *reinterpret_cast<const uint4*>(p);
    return __builtin_bit_cast(bf16x8, v);
}
__device__ __forceinline__ void gld_lds(const u16* gp, u16* lp) {
    __builtin_amdgcn_global_load_lds(
        (const __attribute__((address_space(1))) u32*)gp,
        (__attribute__((address_space(3))) u32*)lp, 16, 0, 0);
}
__device__ __forceinline__ u32 pk_bf16(float lo, float hi) {
    u32 r;
    asm("v_cvt_pk_bf16_f32 %0, %1, %2" : "=v"(r) : "v"(lo), "v"(hi));
    return r;
}
__device__ __forceinline__ void unp8(uint4 v, float* f) {
    f[0] = bf2f((u16)(v.x & 0xffffu)); f[1] = bf2f((u16)(v.x >> 16));
    f[2] = bf2f((u16)(v.y & 0xffffu)); f[3] = bf2f((u16)(v.y >> 16));
    f[4] = bf2f((u16)(v.z & 0xffffu)); f[5] = bf2f((u16)(v.z >> 16));
    f[6] = bf2f((u16)(v.w & 0xffffu)); f[7] = bf2f((u16)(v.w >> 16));
}

// ---------- fused fp32 -> bf16 convert for x / qkv_w / c_proj_w ----------
__global__ __launch_bounds__(256) void cvt3(const float* __restrict__ x,
                                            const float* __restrict__ w,
                                            const float* __restrict__ c,
                                            u16* __restrict__ xb,
                                            u16* __restrict__ wb,
                                            u16* __restrict__ cb) {
    int b = blockIdx.x;
    const float* in;
    u16* out;
    int i;
    if (b < 4096)      { in = x; out = xb; i = b * 256 + threadIdx.x; }
    else if (b < 7168) { in = w; out = wb; i = (b - 4096) * 256 + threadIdx.x; }
    else               { in = c; out = cb; i = (b - 7168) * 256 + threadIdx.x; }
    float4 v = reinterpret_cast<const float4*>(in)[i];
    u16x4 o;
    o.x = f2bf(v.x); o.y = f2bf(v.y); o.z = f2bf(v.z); o.w = f2bf(v.w);
    *reinterpret_cast<u16x4*>(out + 4 * (size_t)i) = o;
}

// ---------- rope tables: ctab/stab [T=4096][64] fp32 ----------
__global__ __launch_bounds__(256) void rope_tab(float* __restrict__ ctab,
                                                float* __restrict__ stab) {
    int i = blockIdx.x * 256 + threadIdx.x;
    int t = i >> 6, j = i & 63;
    float c = 1.0f, s = 0.0f;
    if (j < 32) {
        float f = exp2f(-10.0f * (float)j / 31.0f);
        float th = (float)t * f;
        c = cosf(th); s = sinf(th);
    }
    ctab[i] = c; stab[i] = s;
}

// ---------- NT GEMM: C[M][N] = A[M][K] * B[N][K]^T, bf16 in, fp32 acc ----------
template <bool OUT_BF16>
__global__ __launch_bounds__(256) void gemm_nt(const u16* __restrict__ A,
                                               const u16* __restrict__ B,
                                               void* __restrict__ Cout,
                                               int M, int N, int K, int ldc) {
    __shared__ u16 sA[2][128 * 32];
    __shared__ u16 sB[2][128 * 32];
    const int tid = threadIdx.x;
    const int w = tid >> 6, l = tid & 63;
    const int mb = M >> 7;
    const int bm = blockIdx.x % mb, bn = blockIdx.x / mb;
    const int g = l >> 4, c16 = l & 15;
    const int srow = l >> 2, ssl = l & 3;
    const int wr = w >> 1, wc = w & 1;

    f32x4 acc[4][4] = {};

    auto stage = [&](int bi, int kt) {
#pragma unroll
        for (int cc = 0; cc < 2; ++cc) {
            int c = 2 * w + cc;
            int r = 16 * c + srow;
            int gs = ssl ^ ((r >> 1) & 3);
            gld_lds(A + (size_t)(bm * 128 + r) * K + kt * 32 + gs * 8, &sA[bi][c * 512]);
            gld_lds(B + (size_t)(bn * 128 + r) * K + kt * 32 + gs * 8, &sB[bi][c * 512]);
        }
    };

    const int NT = K >> 5;
    stage(0, 0);
    __syncthreads();
    for (int kt = 0; kt < NT; ++kt) {
        int cur = kt & 1;
        if (kt + 1 < NT) stage(cur ^ 1, kt + 1);
        bf16x8 af[4], bf[4];
#pragma unroll
        for (int mi = 0; mi < 4; ++mi) {
            int r = wr * 64 + mi * 16 + c16;
            int sl = g ^ ((r >> 1) & 3);
            af[mi] = ld_frag(&sA[cur][r * 32 + sl * 8]);
        }
#pragma unroll
        for (int ni = 0; ni < 4; ++ni) {
            int r = wc * 64 + ni * 16 + c16;
            int sl = g ^ ((r >> 1) & 3);
            bf[ni] = ld_frag(&sB[cur][r * 32 + sl * 8]);
        }
#pragma unroll
        for (int mi = 0; mi < 4; ++mi)
#pragma unroll
            for (int ni = 0; ni < 4; ++ni)
                acc[mi][ni] = __builtin_amdgcn_mfma_f32_16x16x32_bf16(
                    af[mi], bf[ni], acc[mi][ni], 0, 0, 0);
        __syncthreads();
    }
#pragma unroll
    for (int mi = 0; mi < 4; ++mi) {
#pragma unroll
        for (int ni = 0; ni < 4; ++ni) {
            int col = bn * 128 + wc * 64 + ni * 16 + c16;
            int row0 = bm * 128 + wr * 64 + mi * 16 + g * 4;
#pragma unroll
            for (int r = 0; r < 4; ++r) {
                if (OUT_BF16)
                    ((u16*)Cout)[(size_t)(row0 + r) * ldc + col] = f2bf(acc[mi][ni][r]);
                else
                    ((float*)Cout)[(size_t)(row0 + r) * ldc + col] = acc[mi][ni][r];
            }
        }
    }
}

// ---------- prep: rmsnorm+rope on q,k (q pre-scaled by ATTN_SCALE); v-mix ----------
// Qb,Kb: [H][T][128] bf16 ; Vt: [H][128][T] bf16
__global__ __launch_bounds__(256) void prep(const u16* __restrict__ qkvb,
                                            const float* __restrict__ ve,
                                            const float* __restrict__ lambdas,
                                            const float* __restrict__ ctab,
                                            const float* __restrict__ stab,
                                            u16* __restrict__ Qb, u16* __restrict__ Kb,
                                            u16* __restrict__ Vt) {
    __shared__ u16 sV[128 * 72];
    const int h = blockIdx.x >> 6, tb = blockIdx.x & 63;
    const int tid = threadIdx.x;
    const int trow = tid >> 2, p = tid & 3;
    const int t = tb * 64 + trow;
    const float l0 = lambdas[0], l1 = lambdas[1];

#pragma unroll
    for (int which = 0; which < 2; ++which) {
        const u16* src = qkvb + (size_t)t * 3072 + which * 1024 + h * 128;
        int j0 = p * 16;
        float x1[16], x2[16];
        unp8(*(const uint4*)(src + j0), x1);
        unp8(*(const uint4*)(src + j0 + 8), x1 + 8);
        unp8(*(const uint4*)(src + 64 + j0), x2);
        unp8(*(const uint4*)(src + 64 + j0 + 8), x2 + 8);
        float ss = 0.0f;
#pragma unroll
        for (int e = 0; e < 16; ++e) ss += x1[e] * x1[e] + x2[e] * x2[e];
        ss += __shfl_xor(ss, 1);
        ss += __shfl_xor(ss, 2);
        float rs = rsqrtf(ss * (1.0f / 128.0f) + 1.1920929e-07f);
        float scl = which ? 1.0f : 0.12f;
        rs *= scl;
        u16* dst = (which ? Kb : Qb) + ((size_t)h * 4096 + t) * 128;
#pragma unroll
        for (int e = 0; e < 16; ++e) {
            int j = j0 + e;
            float c = ctab[t * 64 + j], s = stab[t * 64 + j];
            float a = x1[e] * rs, b = x2[e] * rs;
            dst[j] = f2bf(a * c + b * s);
            dst[j + 64] = f2bf(b * c - a * s);
        }
    }
    {
        const u16* vsrc = qkvb + (size_t)t * 3072 + 2048 + h * 128 + p * 32;
        const float* vesrc = ve + (size_t)t * 1024 + h * 128 + p * 32;
#pragma unroll
        for (int q8 = 0; q8 < 4; ++q8) {
            float vf[8];
            unp8(*(const uint4*)(vsrc + q8 * 8), vf);
            float4 e0 = *(const float4*)(vesrc + q8 * 8);
            float4 e1 = *(const float4*)(vesrc + q8 * 8 + 4);
            float ee[8] = {e0.x, e0.y, e0.z, e0.w, e1.x, e1.y, e1.z, e1.w};
#pragma unroll
            for (int j = 0; j < 8; ++j) {
                float vv = l0 * vf[j] + l1 * ee[j];
                sV[(p * 32 + q8 * 8 + j) * 72 + trow] = f2bf(vv);
            }
        }
    }
    __syncthreads();
    {
        int d = tid >> 1, seg = tid & 1;
        const u16* lsrc = &sV[d * 72 + seg * 32];
        u16* gdst = Vt + ((size_t)h * 128 + d) * 4096 + tb * 64 + seg * 32;
#pragma unroll
        for (int q2 = 0; q2 < 4; ++q2)
            *(uint4*)(gdst + q2 * 8) = *(const uint4*)(lsrc + q2 * 8);
    }
}

// ---------- causal flash attention v4 ----------
// R2 structure (4 waves x 16 q, KVBLK=64, dbuf K/V) with:
//  - no-max softmax: rmsnorm'd q,k * 0.12 bound |S|<=15.4 -> exp(S) safe in
//    fp32/bf16; deletes running max, rescale, and per-tile shuffle reduces.
//  - complementary static schedule: bid and bid+256 sum to 65 tiles.
__global__ __launch_bounds__(256) void attn(const u16* __restrict__ Qb,
                                            const u16* __restrict__ Kb,
                                            const u16* __restrict__ Vt,
                                            u16* __restrict__ Y) {
    __shared__ u16 sK[2][64 * 128];   // [kv][d], slot ^= (kv&7)
    __shared__ u16 sV[2][128 * 64];   // [d][kv], slot ^= (d&7)
    __shared__ u16 sP[4][16 * 64];    // per-wave P^T [q][kv], slot ^= (q&7)
    const int bid = blockIdx.x;
    const int h = bid & 7;                       // head -> XCD affinity
    const int pid = bid >> 3;
    const int qb = (pid < 32) ? (63 - pid) : (pid - 32);   // bid & bid+256 complementary
    const int tid = threadIdx.x;
    const int w = tid >> 6, l = tid & 63;
    const int g = l >> 4, q16 = l & 15;
    const int qg = qb * 64 + w * 16 + q16;       // this lane's q row (global)

    bf16x8 qf[4];
    {
        const u16* qp = Qb + ((size_t)h * 4096 + qg) * 128;
#pragma unroll
        for (int dk = 0; dk < 4; ++dk) qf[dk] = ld_frag(qp + dk * 32 + g * 8);
    }

    f32x4 o[8] = {};
    float ssum = 0.0f;                 // per-lane partial; reduced once at end
    u16* sPw = &sP[w][0];

    auto stage = [&](int bi, int t) {
#pragma unroll
        for (int cc = 0; cc < 4; ++cc) {
            int c = 4 * w + cc;
            {
                int r = 4 * c + (l >> 4);
                int gs = (l & 15) ^ (r & 7);
                gld_lds(Kb + ((size_t)h * 4096 + t * 64 + r) * 128 + gs * 8, &sK[bi][c * 512]);
            }
            {
                int r = 8 * c + (l >> 3);
                int gs = (l & 7) ^ (r & 7);
                gld_lds(Vt + ((size_t)h * 128 + r) * 4096 + t * 64 + gs * 8, &sV[bi][c * 512]);
            }
        }
    };

    stage(0, 0);
    __syncthreads();

    const int nt = qb + 1;
    for (int t = 0; t < nt; ++t) {
        const int cur = t & 1;
        if (t + 1 < nt) stage(cur ^ 1, t + 1);   // drained by end-of-loop barrier

        // S^T = K · Q
        f32x4 st[4] = {};
        __builtin_amdgcn_s_setprio(1);
#pragma unroll
        for (int ct = 0; ct < 4; ++ct) {
            int row = ct * 16 + q16;
#pragma unroll
            for (int dk = 0; dk < 4; ++dk) {
                int sl = (dk * 4 + g) ^ (row & 7);
                bf16x8 kf = ld_frag(&sK[cur][row * 128 + sl * 8]);
                st[ct] = __builtin_amdgcn_mfma_f32_16x16x32_bf16(kf, qf[dk], st[ct], 0, 0, 0);
            }
        }
        __builtin_amdgcn_s_setprio(0);

        // no-max softmax: pv = exp(S) directly (|S| <= ~15.4 by construction)
        float pv[16];
        if (t == qb) {
#pragma unroll
            for (int ct = 0; ct < 4; ++ct)
#pragma unroll
                for (int r = 0; r < 4; ++r) {
                    int kvg = t * 64 + ct * 16 + g * 4 + r;
                    pv[ct * 4 + r] = (kvg <= qg) ? __expf(st[ct][r]) : 0.0f;
                }
        } else {
#pragma unroll
            for (int ct = 0; ct < 4; ++ct)
#pragma unroll
                for (int r = 0; r < 4; ++r)
                    pv[ct * 4 + r] = __expf(st[ct][r]);
        }
        float ps = 0.0f;
#pragma unroll
        for (int i = 0; i < 16; ++i) ps += pv[i];
        ssum += ps;

        // pack P -> sPw[q][kv] (b32 writes, slot ^= q&7)
#pragma unroll
        for (int ct = 0; ct < 4; ++ct)
#pragma unroll
            for (int rp = 0; rp < 2; ++rp) {
                u32 pk = pk_bf16(pv[ct * 4 + 2 * rp], pv[ct * 4 + 2 * rp + 1]);
                int cu = 8 * ct + 2 * g + rp;
                int slot = cu >> 2, within = cu & 3;
                *(u32*)((char*)sPw + q16 * 128 + ((slot ^ (q16 & 7)) << 4) + within * 4) = pk;
            }
        asm volatile("s_waitcnt lgkmcnt(0)" ::: "memory");
        __builtin_amdgcn_sched_barrier(0);

        // O^T += V^T · P^T
        __builtin_amdgcn_s_setprio(1);
#pragma unroll
        for (int kk = 0; kk < 2; ++kk) {
            int slr = (4 * kk + g) ^ (q16 & 7);
            bf16x8 pb = ld_frag((const u16*)((const char*)sPw + q16 * 128 + (slr << 4)));
#pragma unroll
            for (int n8 = 0; n8 < 8; ++n8) {
                int row = n8 * 16 + q16;
                int sl = (4 * kk + g) ^ (row & 7);
                bf16x8 vf = ld_frag(&sV[cur][row * 64 + sl * 8]);
                o[n8] = __builtin_amdgcn_mfma_f32_16x16x32_bf16(vf, pb, o[n8], 0, 0, 0);
            }
        }
        __builtin_amdgcn_s_setprio(0);
        __syncthreads();   // drains next-tile staging
    }

    // epilogue: reduce ssum across g-groups (same q16), then y = o / ssum
    ssum += __shfl_xor(ssum, 16);
    ssum += __shfl_xor(ssum, 32);
    float inv = 1.0f / ssum;
    u16* yrow = Y + (size_t)qg * 1024 + h * 128;
#pragma unroll
    for (int n8 = 0; n8 < 8; ++n8) {
        int d0 = n8 * 16 + g * 4;
        u16x4 ov;
        ov.x = f2bf(o[n8][0] * inv);
        ov.y = f2bf(o[n8][1] * inv);
        ov.z = f2bf(o[n8][2] * inv);
        ov.w = f2bf(o[n8][3] * inv);
        *(u16x4*)(yrow + d0) = ov;
    }
}

// ---------- launch ----------
extern "C" void kernel_launch(void* const* d_in, const int* in_sizes, int n_in,
                              void* d_out, int out_size, void* d_ws, size_t ws_size,
                              hipStream_t stream) {
    const float* x = (const float*)d_in[0];
    const float* ve = (const float*)d_in[1];
    const float* qkv_w = (const float*)d_in[2];
    const float* lambdas = (const float*)d_in[3];
    const float* c_proj_w = (const float*)d_in[4];

    char* ws = (char*)d_ws;
    size_t o = 0;
    u16* qkvb = (u16*)(ws + o); o += (size_t)4096 * 3072 * 2;
    u16* xb   = (u16*)(ws + o); o += (size_t)4096 * 1024 * 2;
    u16* wb   = (u16*)(ws + o); o += (size_t)3072 * 1024 * 2;
    u16* cb   = (u16*)(ws + o); o += (size_t)1024 * 1024 * 2;
    u16* Qb   = (u16*)(ws + o); o += (size_t)8 * 4096 * 128 * 2;
    u16* Kb   = (u16*)(ws + o); o += (size_t)8 * 4096 * 128 * 2;
    u16* Vt   = (u16*)(ws + o); o += (size_t)8 * 4096 * 128 * 2;
    u16* Yb   = (u16*)(ws + o); o += (size_t)4096 * 1024 * 2;
    float* ctab = (float*)(ws + o); o += (size_t)4096 * 64 * 4;
    float* stab = (float*)(ws + o); o += (size_t)4096 * 64 * 4;

    cvt3<<<8192, 256, 0, stream>>>(x, qkv_w, c_proj_w, xb, wb, cb);
    rope_tab<<<1024, 256, 0, stream>>>(ctab, stab);
    gemm_nt<true><<<32 * 24, 256, 0, stream>>>(xb, wb, qkvb, 4096, 3072, 1024, 3072);
    prep<<<512, 256, 0, stream>>>(qkvb, ve, lambdas, ctab, stab, Qb, Kb, Vt);
    attn<<<512, 256, 0, stream>>>(Qb, Kb, Vt, Yb);
    gemm_nt<false><<<32 * 8, 256, 0, stream>>>(Yb, cb, d_out, 4096, 1024, 1024, 1024);
}

// Round 5
// 171.674 us; speedup vs baseline: 1.4637x; 1.0233x over previous
//
#include <hip/hip_runtime.h>
#include <hip/hip_bf16.h>

typedef __attribute__((ext_vector_type(4))) float f32x4;
typedef __attribute__((ext_vector_type(8))) __bf16 bf16x8;
typedef unsigned short u16;
typedef unsigned int u32;
typedef __attribute__((ext_vector_type(4))) u16 u16x4;

// ---------- helpers ----------
__device__ __forceinline__ u16 f2bf(float f) {
    u32 u = __builtin_bit_cast(u32, f);
    u32 r = (u + 0x7FFFu + ((u >> 16) & 1u)) >> 16;
    return (u16)r;
}
__device__ __forceinline__ float bf2f(u16 h) {
    return __builtin_bit_cast(float, ((u32)h) << 16);
}
__device__ __forceinline__ bf16x8 ld_frag(const u16* p) {
    uint4 v = *reinterpret_cast<const uint4*>(p);
    return __builtin_bit_cast(bf16x8, v);
}
__device__ __forceinline__ void gld_lds(const u16* gp, u16* lp) {
    __builtin_amdgcn_global_load_lds(
        (const __attribute__((address_space(1))) u32*)gp,
        (__attribute__((address_space(3))) u32*)lp, 16, 0, 0);
}
__device__ __forceinline__ u32 pk_bf16(float lo, float hi) {
    u32 r;
    asm("v_cvt_pk_bf16_f32 %0, %1, %2" : "=v"(r) : "v"(lo), "v"(hi));
    return r;
}
__device__ __forceinline__ void unp8(uint4 v, float* f) {
    f[0] = bf2f((u16)(v.x & 0xffffu)); f[1] = bf2f((u16)(v.x >> 16));
    f[2] = bf2f((u16)(v.y & 0xffffu)); f[3] = bf2f((u16)(v.y >> 16));
    f[4] = bf2f((u16)(v.z & 0xffffu)); f[5] = bf2f((u16)(v.z >> 16));
    f[6] = bf2f((u16)(v.w & 0xffffu)); f[7] = bf2f((u16)(v.w >> 16));
}

// ---------- fused fp32 -> bf16 convert for x / qkv_w / c_proj_w ----------
__global__ __launch_bounds__(256) void cvt3(const float* __restrict__ x,
                                            const float* __restrict__ w,
                                            const float* __restrict__ c,
                                            u16* __restrict__ xb,
                                            u16* __restrict__ wb,
                                            u16* __restrict__ cb) {
    int b = blockIdx.x;
    const float* in;
    u16* out;
    int i;
    if (b < 4096)      { in = x; out = xb; i = b * 256 + threadIdx.x; }
    else if (b < 7168) { in = w; out = wb; i = (b - 4096) * 256 + threadIdx.x; }
    else               { in = c; out = cb; i = (b - 7168) * 256 + threadIdx.x; }
    float4 v = reinterpret_cast<const float4*>(in)[i];
    u16x4 o;
    o.x = f2bf(v.x); o.y = f2bf(v.y); o.z = f2bf(v.z); o.w = f2bf(v.w);
    *reinterpret_cast<u16x4*>(out + 4 * (size_t)i) = o;
}

// ---------- rope tables: ctab/stab [T=4096][64] fp32 ----------
__global__ __launch_bounds__(256) void rope_tab(float* __restrict__ ctab,
                                                float* __restrict__ stab) {
    int i = blockIdx.x * 256 + threadIdx.x;
    int t = i >> 6, j = i & 63;
    float c = 1.0f, s = 0.0f;
    if (j < 32) {
        float f = exp2f(-10.0f * (float)j / 31.0f);
        float th = (float)t * f;
        c = cosf(th); s = sinf(th);
    }
    ctab[i] = c; stab[i] = s;
}

// ---------- NT GEMM: C[M][N] = A[M][K] * B[N][K]^T, bf16 in, fp32 acc ----------
template <bool OUT_BF16>
__global__ __launch_bounds__(256) void gemm_nt(const u16* __restrict__ A,
                                               const u16* __restrict__ B,
                                               void* __restrict__ Cout,
                                               int M, int N, int K, int ldc) {
    __shared__ u16 sA[2][128 * 32];
    __shared__ u16 sB[2][128 * 32];
    const int tid = threadIdx.x;
    const int w = tid >> 6, l = tid & 63;
    const int mb = M >> 7;
    const int bm = blockIdx.x % mb, bn = blockIdx.x / mb;
    const int g = l >> 4, c16 = l & 15;
    const int srow = l >> 2, ssl = l & 3;
    const int wr = w >> 1, wc = w & 1;

    f32x4 acc[4][4] = {};

    auto stage = [&](int bi, int kt) {
#pragma unroll
        for (int cc = 0; cc < 2; ++cc) {
            int c = 2 * w + cc;
            int r = 16 * c + srow;
            int gs = ssl ^ ((r >> 1) & 3);
            gld_lds(A + (size_t)(bm * 128 + r) * K + kt * 32 + gs * 8, &sA[bi][c * 512]);
            gld_lds(B + (size_t)(bn * 128 + r) * K + kt * 32 + gs * 8, &sB[bi][c * 512]);
        }
    };

    const int NT = K >> 5;
    stage(0, 0);
    __syncthreads();
    for (int kt = 0; kt < NT; ++kt) {
        int cur = kt & 1;
        if (kt + 1 < NT) stage(cur ^ 1, kt + 1);
        bf16x8 af[4], bf[4];
#pragma unroll
        for (int mi = 0; mi < 4; ++mi) {
            int r = wr * 64 + mi * 16 + c16;
            int sl = g ^ ((r >> 1) & 3);
            af[mi] = ld_frag(&sA[cur][r * 32 + sl * 8]);
        }
#pragma unroll
        for (int ni = 0; ni < 4; ++ni) {
            int r = wc * 64 + ni * 16 + c16;
            int sl = g ^ ((r >> 1) & 3);
            bf[ni] = ld_frag(&sB[cur][r * 32 + sl * 8]);
        }
#pragma unroll
        for (int mi = 0; mi < 4; ++mi)
#pragma unroll
            for (int ni = 0; ni < 4; ++ni)
                acc[mi][ni] = __builtin_amdgcn_mfma_f32_16x16x32_bf16(
                    af[mi], bf[ni], acc[mi][ni], 0, 0, 0);
        __syncthreads();
    }
#pragma unroll
    for (int mi = 0; mi < 4; ++mi) {
#pragma unroll
        for (int ni = 0; ni < 4; ++ni) {
            int col = bn * 128 + wc * 64 + ni * 16 + c16;
            int row0 = bm * 128 + wr * 64 + mi * 16 + g * 4;
#pragma unroll
            for (int r = 0; r < 4; ++r) {
                if (OUT_BF16)
                    ((u16*)Cout)[(size_t)(row0 + r) * ldc + col] = f2bf(acc[mi][ni][r]);
                else
                    ((float*)Cout)[(size_t)(row0 + r) * ldc + col] = acc[mi][ni][r];
            }
        }
    }
}

// ---------- prep: rmsnorm+rope on q,k (q pre-scaled by ATTN_SCALE); v-mix ----------
// Qb,Kb: [H][T][128] bf16 ; Vt: [H][128][T] bf16 with tokens PERMUTED within
// each 64-block: column c(t) = (t&3) | ((t>>4)&1)<<2 | ((t>>2)&3)<<3 | (t>>5)<<5
// so that attn's in-register P fragments line up with V's MFMA A-operand slots.
__global__ __launch_bounds__(256) void prep(const u16* __restrict__ qkvb,
                                            const float* __restrict__ ve,
                                            const float* __restrict__ lambdas,
                                            const float* __restrict__ ctab,
                                            const float* __restrict__ stab,
                                            u16* __restrict__ Qb, u16* __restrict__ Kb,
                                            u16* __restrict__ Vt) {
    __shared__ u16 sV[128 * 72];
    const int h = blockIdx.x >> 6, tb = blockIdx.x & 63;
    const int tid = threadIdx.x;
    const int trow = tid >> 2, p = tid & 3;
    const int t = tb * 64 + trow;
    const float l0 = lambdas[0], l1 = lambdas[1];
    // permuted column for V within the 64-token block
    const int cperm = (trow & 3) | (((trow >> 4) & 1) << 2) | (((trow >> 2) & 3) << 3)
                    | ((trow >> 5) << 5);

#pragma unroll
    for (int which = 0; which < 2; ++which) {
        const u16* src = qkvb + (size_t)t * 3072 + which * 1024 + h * 128;
        int j0 = p * 16;
        float x1[16], x2[16];
        unp8(*(const uint4*)(src + j0), x1);
        unp8(*(const uint4*)(src + j0 + 8), x1 + 8);
        unp8(*(const uint4*)(src + 64 + j0), x2);
        unp8(*(const uint4*)(src + 64 + j0 + 8), x2 + 8);
        float ss = 0.0f;
#pragma unroll
        for (int e = 0; e < 16; ++e) ss += x1[e] * x1[e] + x2[e] * x2[e];
        ss += __shfl_xor(ss, 1);
        ss += __shfl_xor(ss, 2);
        float rs = rsqrtf(ss * (1.0f / 128.0f) + 1.1920929e-07f);
        float scl = which ? 1.0f : 0.12f;
        rs *= scl;
        u16* dst = (which ? Kb : Qb) + ((size_t)h * 4096 + t) * 128;
#pragma unroll
        for (int e = 0; e < 16; ++e) {
            int j = j0 + e;
            float c = ctab[t * 64 + j], s = stab[t * 64 + j];
            float a = x1[e] * rs, b = x2[e] * rs;
            dst[j] = f2bf(a * c + b * s);
            dst[j + 64] = f2bf(b * c - a * s);
        }
    }
    {
        const u16* vsrc = qkvb + (size_t)t * 3072 + 2048 + h * 128 + p * 32;
        const float* vesrc = ve + (size_t)t * 1024 + h * 128 + p * 32;
#pragma unroll
        for (int q8 = 0; q8 < 4; ++q8) {
            float vf[8];
            unp8(*(const uint4*)(vsrc + q8 * 8), vf);
            float4 e0 = *(const float4*)(vesrc + q8 * 8);
            float4 e1 = *(const float4*)(vesrc + q8 * 8 + 4);
            float ee[8] = {e0.x, e0.y, e0.z, e0.w, e1.x, e1.y, e1.z, e1.w};
#pragma unroll
            for (int j = 0; j < 8; ++j) {
                float vv = l0 * vf[j] + l1 * ee[j];
                sV[(p * 32 + q8 * 8 + j) * 72 + cperm] = f2bf(vv);
            }
        }
    }
    __syncthreads();
    {
        int d = tid >> 1, seg = tid & 1;
        const u16* lsrc = &sV[d * 72 + seg * 32];
        u16* gdst = Vt + ((size_t)h * 128 + d) * 4096 + tb * 64 + seg * 32;
#pragma unroll
        for (int q2 = 0; q2 < 4; ++q2)
            *(uint4*)(gdst + q2 * 8) = *(const uint4*)(lsrc + q2 * 8);
    }
}

// ---------- causal flash attention v5 ----------
// R4 structure + register-P: V tokens pre-permuted (prep) so each lane's
// pv[8kk..8kk+7] IS the PV B-fragment -> P never touches LDS; no lgkmcnt
// serialization point; compiler free to overlap V-reads with softmax.
__global__ __launch_bounds__(256) void attn(const u16* __restrict__ Qb,
                                            const u16* __restrict__ Kb,
                                            const u16* __restrict__ Vt,
                                            u16* __restrict__ Y) {
    __shared__ u16 sK[2][64 * 128];   // [kv][d], slot ^= (kv&7)
    __shared__ u16 sV[2][128 * 64];   // [d][kv-permuted], slot ^= (d&7)
    const int bid = blockIdx.x;
    const int h = bid & 7;                       // head -> XCD affinity
    const int pid = bid >> 3;
    const int qb = (pid < 32) ? (63 - pid) : (pid - 32);   // bid & bid+256 complementary
    const int tid = threadIdx.x;
    const int w = tid >> 6, l = tid & 63;
    const int g = l >> 4, q16 = l & 15;
    const int qg = qb * 64 + w * 16 + q16;       // this lane's q row (global)

    bf16x8 qf[4];
    {
        const u16* qp = Qb + ((size_t)h * 4096 + qg) * 128;
#pragma unroll
        for (int dk = 0; dk < 4; ++dk) qf[dk] = ld_frag(qp + dk * 32 + g * 8);
    }

    f32x4 o[8] = {};
    float ssum = 0.0f;                 // per-lane partial; reduced once at end

    auto stage = [&](int bi, int t) {
#pragma unroll
        for (int cc = 0; cc < 4; ++cc) {
            int c = 4 * w + cc;
            {
                int r = 4 * c + (l >> 4);
                int gs = (l & 15) ^ (r & 7);
                gld_lds(Kb + ((size_t)h * 4096 + t * 64 + r) * 128 + gs * 8, &sK[bi][c * 512]);
            }
            {
                int r = 8 * c + (l >> 3);
                int gs = (l & 7) ^ (r & 7);
                gld_lds(Vt + ((size_t)h * 128 + r) * 4096 + t * 64 + gs * 8, &sV[bi][c * 512]);
            }
        }
    };

    stage(0, 0);
    __syncthreads();

    const int nt = qb + 1;
    for (int t = 0; t < nt; ++t) {
        const int cur = t & 1;
        if (t + 1 < nt) stage(cur ^ 1, t + 1);   // drained by end-of-loop barrier

        // S^T = K · Q
        f32x4 st[4] = {};
        __builtin_amdgcn_s_setprio(1);
#pragma unroll
        for (int ct = 0; ct < 4; ++ct) {
            int row = ct * 16 + q16;
#pragma unroll
            for (int dk = 0; dk < 4; ++dk) {
                int sl = (dk * 4 + g) ^ (row & 7);
                bf16x8 kf = ld_frag(&sK[cur][row * 128 + sl * 8]);
                st[ct] = __builtin_amdgcn_mfma_f32_16x16x32_bf16(kf, qf[dk], st[ct], 0, 0, 0);
            }
        }
        __builtin_amdgcn_s_setprio(0);

        // no-max softmax: pv = exp(S) directly (|S| <= ~15.4 by construction)
        float pv[16];
        if (t == qb) {
#pragma unroll
            for (int ct = 0; ct < 4; ++ct)
#pragma unroll
                for (int r = 0; r < 4; ++r) {
                    int kvg = t * 64 + ct * 16 + g * 4 + r;
                    pv[ct * 4 + r] = (kvg <= qg) ? __expf(st[ct][r]) : 0.0f;
                }
        } else {
#pragma unroll
            for (int ct = 0; ct < 4; ++ct)
#pragma unroll
                for (int r = 0; r < 4; ++r)
                    pv[ct * 4 + r] = __expf(st[ct][r]);
        }
        float ps = 0.0f;
#pragma unroll
        for (int i = 0; i < 16; ++i) ps += pv[i];
        ssum += ps;

        // build PV B-fragments directly in registers (V is token-permuted so
        // pv[8kk+j] sits in exactly the right MFMA k-slot)
        bf16x8 pb[2];
#pragma unroll
        for (int kk = 0; kk < 2; ++kk) {
            uint4 u;
            u.x = pk_bf16(pv[8 * kk + 0], pv[8 * kk + 1]);
            u.y = pk_bf16(pv[8 * kk + 2], pv[8 * kk + 3]);
            u.z = pk_bf16(pv[8 * kk + 4], pv[8 * kk + 5]);
            u.w = pk_bf16(pv[8 * kk + 6], pv[8 * kk + 7]);
            pb[kk] = __builtin_bit_cast(bf16x8, u);
        }

        // O^T += V^T · P^T
        __builtin_amdgcn_s_setprio(1);
#pragma unroll
        for (int kk = 0; kk < 2; ++kk) {
#pragma unroll
            for (int n8 = 0; n8 < 8; ++n8) {
                int row = n8 * 16 + q16;
                int sl = (4 * kk + g) ^ (row & 7);
                bf16x8 vf = ld_frag(&sV[cur][row * 64 + sl * 8]);
                o[n8] = __builtin_amdgcn_mfma_f32_16x16x32_bf16(vf, pb[kk], o[n8], 0, 0, 0);
            }
        }
        __builtin_amdgcn_s_setprio(0);
        __syncthreads();   // drains next-tile staging
    }

    // epilogue: reduce ssum across g-groups (same q16), then y = o / ssum
    ssum += __shfl_xor(ssum, 16);
    ssum += __shfl_xor(ssum, 32);
    float inv = 1.0f / ssum;
    u16* yrow = Y + (size_t)qg * 1024 + h * 128;
#pragma unroll
    for (int n8 = 0; n8 < 8; ++n8) {
        int d0 = n8 * 16 + g * 4;
        u16x4 ov;
        ov.x = f2bf(o[n8][0] * inv);
        ov.y = f2bf(o[n8][1] * inv);
        ov.z = f2bf(o[n8][2] * inv);
        ov.w = f2bf(o[n8][3] * inv);
        *(u16x4*)(yrow + d0) = ov;
    }
}

// ---------- launch ----------
extern "C" void kernel_launch(void* const* d_in, const int* in_sizes, int n_in,
                              void* d_out, int out_size, void* d_ws, size_t ws_size,
                              hipStream_t stream) {
    const float* x = (const float*)d_in[0];
    const float* ve = (const float*)d_in[1];
    const float* qkv_w = (const float*)d_in[2];
    const float* lambdas = (const float*)d_in[3];
    const float* c_proj_w = (const float*)d_in[4];

    char* ws = (char*)d_ws;
    size_t o = 0;
    u16* qkvb = (u16*)(ws + o); o += (size_t)4096 * 3072 * 2;
    u16* xb   = (u16*)(ws + o); o += (size_t)4096 * 1024 * 2;
    u16* wb   = (u16*)(ws + o); o += (size_t)3072 * 1024 * 2;
    u16* cb   = (u16*)(ws + o); o += (size_t)1024 * 1024 * 2;
    u16* Qb   = (u16*)(ws + o); o += (size_t)8 * 4096 * 128 * 2;
    u16* Kb   = (u16*)(ws + o); o += (size_t)8 * 4096 * 128 * 2;
    u16* Vt   = (u16*)(ws + o); o += (size_t)8 * 4096 * 128 * 2;
    u16* Yb   = (u16*)(ws + o); o += (size_t)4096 * 1024 * 2;
    float* ctab = (float*)(ws + o); o += (size_t)4096 * 64 * 4;
    float* stab = (float*)(ws + o); o += (size_t)4096 * 64 * 4;

    cvt3<<<8192, 256, 0, stream>>>(x, qkv_w, c_proj_w, xb, wb, cb);
    rope_tab<<<1024, 256, 0, stream>>>(ctab, stab);
    gemm_nt<true><<<32 * 24, 256, 0, stream>>>(xb, wb, qkvb, 4096, 3072, 1024, 3072);
    prep<<<512, 256, 0, stream>>>(qkvb, ve, lambdas, ctab, stab, Qb, Kb, Vt);
    attn<<<512, 256, 0, stream>>>(Qb, Kb, Vt, Yb);
    gemm_nt<false><<<32 * 8, 256, 0, stream>>>(Yb, cb, d_out, 4096, 1024, 1024, 1024);
}